// Round 4
// baseline (5817.635 us; speedup 1.0000x reference)
//
#include <hip/hip_runtime.h>
#include <math.h>
#include <float.h>

#define BLK 256
#define NPT 4                      // nodes per thread (weight-read amortization)
#define TILE (BLK * NPT)           // 1024 nodes per block

// ---------------------------------------------------------------------------
// K0: fast exclusive scan of both count arrays. One block, 1024 threads.
// ---------------------------------------------------------------------------
__device__ __forceinline__ void scan_one(const int* __restrict__ cnt, int n,
                                         int* __restrict__ starts, int* wsum)
{
    const int t = threadIdx.x;
    const int chunk = (n + 1023) / 1024;
    const int base = t * chunk;

    int sum = 0;
    for (int k = 0; k < chunk; k++) {
        int idx = base + k;
        if (idx < n) sum += cnt[idx];
    }

    const int lane = t & 63, wid = t >> 6;
    int v = sum;
#pragma unroll
    for (int off = 1; off < 64; off <<= 1) {
        int y = __shfl_up(v, off);
        if (lane >= off) v += y;
    }
    if (lane == 63) wsum[wid] = v;
    __syncthreads();
    if (wid == 0) {
        int w = (lane < 16) ? wsum[lane] : 0;
#pragma unroll
        for (int off = 1; off < 16; off <<= 1) {
            int y = __shfl_up(w, off);
            if (lane >= off) w += y;
        }
        if (lane < 16) wsum[lane] = w;
    }
    __syncthreads();

    int thr_excl = ((wid > 0) ? wsum[wid - 1] : 0) + v - sum;
    int run = thr_excl;
    for (int k = 0; k < chunk; k++) {
        int idx = base + k;
        if (idx < n) { starts[idx] = run; run += cnt[idx]; }
    }
    if (t == 0) starts[n] = wsum[15];
    __syncthreads();
}

__global__ __launch_bounds__(1024) void scan2_kernel(
    const int* __restrict__ dag_cnt, int nd,
    const int* __restrict__ obs_cnt, int no,
    int* __restrict__ dag_starts, int* __restrict__ obs_starts)
{
    __shared__ int wsum[16];
    scan_one(dag_cnt, nd, dag_starts, wsum);
    scan_one(obs_cnt, no, obs_starts, wsum);
}

// ---------------------------------------------------------------------------
// K1: expand segment ids to per-node arrays (one block per segment).
// ---------------------------------------------------------------------------
__global__ __launch_bounds__(128) void expand_ids_kernel(
    const int* __restrict__ dag_starts, int nd,
    const int* __restrict__ obs_starts, int no,
    int* __restrict__ dag_ids, int* __restrict__ obs_ids)
{
    int seg = blockIdx.x;
    if (seg < nd) {
        int s = dag_starts[seg], e = dag_starts[seg + 1];
        for (int i = s + threadIdx.x; i < e; i += 128) dag_ids[i] = seg;
    } else {
        int g = seg - nd;
        int s = obs_starts[g], e = obs_starts[g + 1];
        for (int i = s + threadIdx.x; i < e; i += 128) obs_ids[i] = g;
    }
}

// ---------------------------------------------------------------------------
// K2: per-segment layer-1 partials (dag rows 37..68 no bias; glob rows 69..100 +b1).
// ---------------------------------------------------------------------------
__global__ __launch_bounds__(256) void seg_h1_kernel(
    const float* __restrict__ dag_sum, int nd,
    const float* __restrict__ glob_sum, int no,
    const float* __restrict__ W1, const float* __restrict__ b1,
    float* __restrict__ dag_h1, float* __restrict__ glob_h1)
{
    __shared__ float Wd[32 * 32];
    __shared__ float Wg[32 * 32];
    for (int t = threadIdx.x; t < 32 * 32; t += 256) {
        int k = t / 32, j = t % 32;
        Wd[t] = W1[(size_t)(37 + k) * 32 + j];
        Wg[t] = W1[(size_t)(69 + k) * 32 + j];
    }
    __syncthreads();

    int gid = blockIdx.x * 256 + threadIdx.x;
    int seg = gid / 32;
    int j   = gid % 32;
    if (seg >= nd + no) return;

    const float* srow;
    const float* Wl;
    float acc;
    float* outp;
    if (seg < nd) {
        srow = dag_sum + (size_t)seg * 32;
        Wl = Wd; acc = 0.f;
        outp = dag_h1 + (size_t)seg * 32 + j;
    } else {
        srow = glob_sum + (size_t)(seg - nd) * 32;
        Wl = Wg; acc = b1[j];
        outp = glob_h1 + (size_t)(seg - nd) * 32 + j;
    }
#pragma unroll
    for (int k = 0; k < 32; k++)
        acc = fmaf(srow[k], Wl[k * 32 + j], acc);
    *outp = acc;
}

// ---------------------------------------------------------------------------
// K3: main MLP, NPT=4 register-blocked. One 1024-node tile per block.
// Weight ds_read_b128 amortized over 4 nodes. NO min-waves bound (spill guard).
// ---------------------------------------------------------------------------
__global__ __launch_bounds__(BLK) void mlp_score_kernel(
    const float* __restrict__ x, const float* __restrict__ emb,
    const float* __restrict__ dag_h1, const float* __restrict__ glob_h1,
    const int* __restrict__ dag_ids, const int* __restrict__ obs_ids,
    const int* __restrict__ mask,
    const float* __restrict__ W1, const float* __restrict__ W2,
    const float* __restrict__ b2, const float* __restrict__ W3,
    const float* __restrict__ b3, const float* __restrict__ W4,
    const float* __restrict__ b4,
    float* __restrict__ scores, float* __restrict__ blk_m,
    double* __restrict__ blk_s, int N)
{
    __shared__ float W1l[37 * 32];
    __shared__ float W2l[32 * 16];
    __shared__ float W3l[16 * 8];
    __shared__ float W4l[8];
    __shared__ float b2l[16];
    __shared__ float b3l[8];
    __shared__ float b4s;

    for (int t = threadIdx.x; t < 37 * 32; t += BLK) W1l[t] = W1[t];
    for (int t = threadIdx.x; t < 32 * 16; t += BLK) W2l[t] = W2[t];
    for (int t = threadIdx.x; t < 16 * 8;  t += BLK) W3l[t] = W3[t];
    if (threadIdx.x < 8)  W4l[threadIdx.x] = W4[threadIdx.x];
    if (threadIdx.x < 16) b2l[threadIdx.x] = b2[threadIdx.x];
    if (threadIdx.x < 8)  b3l[threadIdx.x] = b3[threadIdx.x];
    if (threadIdx.x == 0) b4s = b4[0];
    __syncthreads();

    const int base = blockIdx.x * TILE + threadIdx.x;

    int  idx[NPT];
    bool val[NPT];
#pragma unroll
    for (int r = 0; r < NPT; r++) {
        int i = base + r * BLK;
        val[r] = (i < N);
        idx[r] = val[r] ? i : (N - 1);   // clamped: loads safe, results discarded
    }

    int mk[NPT];
    float h1[NPT][32];
#pragma unroll
    for (int r = 0; r < NPT; r++) {
        const int d = dag_ids[idx[r]];
        const int o = obs_ids[idx[r]];
        mk[r] = mask[idx[r]];
        const float4* dh = (const float4*)(dag_h1 + (size_t)d * 32);
        const float4* gh = (const float4*)(glob_h1 + (size_t)o * 32);
#pragma unroll
        for (int q = 0; q < 8; q++) {
            float4 a = dh[q], b = gh[q];
            h1[r][4 * q + 0] = a.x + b.x;
            h1[r][4 * q + 1] = a.y + b.y;
            h1[r][4 * q + 2] = a.z + b.z;
            h1[r][4 * q + 3] = a.w + b.w;
        }
    }

    // --- x phase: 5 input dims ---
    float xv[NPT][5];
#pragma unroll
    for (int r = 0; r < NPT; r++) {
        const float* xr = x + (size_t)idx[r] * 5;
#pragma unroll
        for (int k = 0; k < 5; k++) xv[r][k] = xr[k];
    }
#pragma unroll
    for (int k = 0; k < 5; k++) {
#pragma unroll
        for (int jb = 0; jb < 8; jb++) {
            float4 w = *(const float4*)&W1l[k * 32 + jb * 4];
#pragma unroll
            for (int r = 0; r < NPT; r++) {
                float v = xv[r][k];
                h1[r][jb * 4 + 0] = fmaf(v, w.x, h1[r][jb * 4 + 0]);
                h1[r][jb * 4 + 1] = fmaf(v, w.y, h1[r][jb * 4 + 1]);
                h1[r][jb * 4 + 2] = fmaf(v, w.z, h1[r][jb * 4 + 2]);
                h1[r][jb * 4 + 3] = fmaf(v, w.w, h1[r][jb * 4 + 3]);
            }
        }
    }

    // --- emb phase: 32 input dims, W row read once per (k), used 4x ---
#pragma unroll
    for (int q = 0; q < 8; q++) {
        float4 e[NPT];
#pragma unroll
        for (int r = 0; r < NPT; r++)
            e[r] = *(const float4*)(emb + (size_t)idx[r] * 32 + q * 4);
#pragma unroll
        for (int kk = 0; kk < 4; kk++) {
            const int k = 5 + q * 4 + kk;
#pragma unroll
            for (int jb = 0; jb < 8; jb++) {
                float4 w = *(const float4*)&W1l[k * 32 + jb * 4];
#pragma unroll
                for (int r = 0; r < NPT; r++) {
                    float v = (kk == 0) ? e[r].x : (kk == 1) ? e[r].y
                            : (kk == 2) ? e[r].z : e[r].w;
                    h1[r][jb * 4 + 0] = fmaf(v, w.x, h1[r][jb * 4 + 0]);
                    h1[r][jb * 4 + 1] = fmaf(v, w.y, h1[r][jb * 4 + 1]);
                    h1[r][jb * 4 + 2] = fmaf(v, w.z, h1[r][jb * 4 + 2]);
                    h1[r][jb * 4 + 3] = fmaf(v, w.w, h1[r][jb * 4 + 3]);
                }
            }
        }
    }
#pragma unroll
    for (int r = 0; r < NPT; r++)
#pragma unroll
        for (int j = 0; j < 32; j++) h1[r][j] = fmaxf(h1[r][j], 0.f);

    // --- layer 2: 32 -> 16 ---
    float h2[NPT][16];
#pragma unroll
    for (int r = 0; r < NPT; r++)
#pragma unroll
        for (int j = 0; j < 16; j++) h2[r][j] = b2l[j];
#pragma unroll
    for (int k = 0; k < 32; k++) {
#pragma unroll
        for (int jb = 0; jb < 4; jb++) {
            float4 w = *(const float4*)&W2l[k * 16 + jb * 4];
#pragma unroll
            for (int r = 0; r < NPT; r++) {
                float v = h1[r][k];
                h2[r][jb * 4 + 0] = fmaf(v, w.x, h2[r][jb * 4 + 0]);
                h2[r][jb * 4 + 1] = fmaf(v, w.y, h2[r][jb * 4 + 1]);
                h2[r][jb * 4 + 2] = fmaf(v, w.z, h2[r][jb * 4 + 2]);
                h2[r][jb * 4 + 3] = fmaf(v, w.w, h2[r][jb * 4 + 3]);
            }
        }
    }
#pragma unroll
    for (int r = 0; r < NPT; r++)
#pragma unroll
        for (int j = 0; j < 16; j++) h2[r][j] = fmaxf(h2[r][j], 0.f);

    // --- layer 3: 16 -> 8 ---
    float h3[NPT][8];
#pragma unroll
    for (int r = 0; r < NPT; r++)
#pragma unroll
        for (int j = 0; j < 8; j++) h3[r][j] = b3l[j];
#pragma unroll
    for (int k = 0; k < 16; k++) {
#pragma unroll
        for (int jb = 0; jb < 2; jb++) {
            float4 w = *(const float4*)&W3l[k * 8 + jb * 4];
#pragma unroll
            for (int r = 0; r < NPT; r++) {
                float v = h2[r][k];
                h3[r][jb * 4 + 0] = fmaf(v, w.x, h3[r][jb * 4 + 0]);
                h3[r][jb * 4 + 1] = fmaf(v, w.y, h3[r][jb * 4 + 1]);
                h3[r][jb * 4 + 2] = fmaf(v, w.z, h3[r][jb * 4 + 2]);
                h3[r][jb * 4 + 3] = fmaf(v, w.w, h3[r][jb * 4 + 3]);
            }
        }
    }
#pragma unroll
    for (int r = 0; r < NPT; r++)
#pragma unroll
        for (int j = 0; j < 8; j++) h3[r][j] = fmaxf(h3[r][j], 0.f);

    // --- layer 4 + masked score + per-thread online softmax ---
    float4 w40 = *(const float4*)&W4l[0];
    float4 w41 = *(const float4*)&W4l[4];
    float m = -INFINITY;
    double ssum = 0.0;
#pragma unroll
    for (int r = 0; r < NPT; r++) {
        float s = b4s;
        s = fmaf(h3[r][0], w40.x, s); s = fmaf(h3[r][1], w40.y, s);
        s = fmaf(h3[r][2], w40.z, s); s = fmaf(h3[r][3], w40.w, s);
        s = fmaf(h3[r][4], w41.x, s); s = fmaf(h3[r][5], w41.y, s);
        s = fmaf(h3[r][6], w41.z, s); s = fmaf(h3[r][7], w41.w, s);

        const bool live = val[r] && (mk[r] != 0);
        if (val[r]) scores[idx[r]] = (mk[r] != 0) ? s : -FLT_MAX;
        if (live) {
            if (s > m) { ssum *= (double)expf(m - s); m = s; }
            ssum += (double)expf(s - m);
        }
    }

    // --- block (m, sum) merge ---
    __shared__ float  mred[BLK];
    __shared__ double sred[BLK];
    mred[threadIdx.x] = m;
    sred[threadIdx.x] = ssum;
    __syncthreads();
    for (int off = BLK / 2; off > 0; off >>= 1) {
        if (threadIdx.x < off) {
            float ma = mred[threadIdx.x], mb = mred[threadIdx.x + off];
            double sa = sred[threadIdx.x], sb = sred[threadIdx.x + off];
            float M = fmaxf(ma, mb);
            double out = 0.0;
            if (ma > -INFINITY) out += sa * (double)expf(ma - M);
            if (mb > -INFINITY) out += sb * (double)expf(mb - M);
            mred[threadIdx.x] = M;
            sred[threadIdx.x] = out;
        }
        __syncthreads();
    }
    if (threadIdx.x == 0) {
        blk_m[blockIdx.x] = mred[0];
        blk_s[blockIdx.x] = sred[0];
    }
}

// ---------------------------------------------------------------------------
// K4: merge per-block (m, s) pairs -> gmax, Z. One block.
// ---------------------------------------------------------------------------
__global__ __launch_bounds__(1024) void merge_kernel(
    const float* __restrict__ bm, const double* __restrict__ bs, int n,
    float* __restrict__ gmax, double* __restrict__ Z)
{
    float m = -INFINITY;
    double s = 0.0;
    for (int i = threadIdx.x; i < n; i += 1024) {
        float mb = bm[i]; double sb = bs[i];
        float M = fmaxf(m, mb);
        double out = 0.0;
        if (m  > -INFINITY) out += s  * (double)expf(m  - M);
        if (mb > -INFINITY) out += sb * (double)expf(mb - M);
        m = M; s = out;
    }
    __shared__ float  mred[1024];
    __shared__ double sred[1024];
    mred[threadIdx.x] = m;
    sred[threadIdx.x] = s;
    __syncthreads();
    for (int off = 512; off > 0; off >>= 1) {
        if (threadIdx.x < off) {
            float ma = mred[threadIdx.x], mb = mred[threadIdx.x + off];
            double sa = sred[threadIdx.x], sb = sred[threadIdx.x + off];
            float M = fmaxf(ma, mb);
            double out = 0.0;
            if (ma > -INFINITY) out += sa * (double)expf(ma - M);
            if (mb > -INFINITY) out += sb * (double)expf(mb - M);
            mred[threadIdx.x] = M;
            sred[threadIdx.x] = out;
        }
        __syncthreads();
    }
    if (threadIdx.x == 0) { *gmax = mred[0]; *Z = sred[0]; }
}

// ---------------------------------------------------------------------------
// K5: finalize out[i] = exp(s - gmax) / Z  (masked -FLT_MAX -> exactly 0).
// ---------------------------------------------------------------------------
__global__ __launch_bounds__(BLK) void finalize_kernel(
    const float* __restrict__ scores, int N,
    const float* __restrict__ gmaxp, const double* __restrict__ Zp,
    float* __restrict__ outp)
{
    const float gm = *gmaxp;
    const float rZ = (float)(1.0 / *Zp);
    int i = blockIdx.x * BLK + threadIdx.x;
    if (i < N) outp[i] = expf(scores[i] - gm) * rZ;
}

// ---------------------------------------------------------------------------
extern "C" void kernel_launch(void* const* d_in, const int* in_sizes, int n_in,
                              void* d_out, int out_size, void* d_ws, size_t ws_size,
                              hipStream_t stream)
{
    const float* x        = (const float*)d_in[0];
    const float* emb      = (const float*)d_in[1];
    const float* dag_sum  = (const float*)d_in[2];
    const float* glob_sum = (const float*)d_in[3];
    const int*   dag_cnt  = (const int*)d_in[4];
    const int*   obs_cnt  = (const int*)d_in[5];
    const int*   mask     = (const int*)d_in[6];   // bool staged as int32
    const float* W1 = (const float*)d_in[7];
    const float* b1 = (const float*)d_in[8];
    const float* W2 = (const float*)d_in[9];
    const float* b2 = (const float*)d_in[10];
    const float* W3 = (const float*)d_in[11];
    const float* b3 = (const float*)d_in[12];
    const float* W4 = (const float*)d_in[13];
    const float* b4 = (const float*)d_in[14];
    float* outp = (float*)d_out;

    const int N  = in_sizes[0] / 5;   // 2,000,000
    const int nd = in_sizes[4];       // 20,000
    const int no = in_sizes[5];       // 1,000

    const int main_blocks = (N + TILE - 1) / TILE;   // 1954

    // --- workspace layout (16B aligned slices) ---
    char* ws = (char*)d_ws;
    size_t off = 0;
    auto alloc = [&](size_t bytes) {
        void* p = ws + off;
        off += (bytes + 15) & ~(size_t)15;
        return p;
    };
    int*    dag_starts = (int*)   alloc((size_t)(nd + 1) * sizeof(int));
    int*    obs_starts = (int*)   alloc((size_t)(no + 1) * sizeof(int));
    int*    dag_ids    = (int*)   alloc((size_t)N * sizeof(int));
    int*    obs_ids    = (int*)   alloc((size_t)N * sizeof(int));
    float*  dag_h1     = (float*) alloc((size_t)nd * 32 * sizeof(float));
    float*  glob_h1    = (float*) alloc((size_t)no * 32 * sizeof(float));
    float*  scores     = (float*) alloc((size_t)N * sizeof(float));
    float*  blk_m      = (float*) alloc((size_t)main_blocks * sizeof(float));
    double* blk_s      = (double*)alloc((size_t)main_blocks * sizeof(double));
    float*  gmax       = (float*) alloc(sizeof(float));
    double* Z          = (double*)alloc(sizeof(double));
    (void)ws_size;

    // K0: prefix scans
    scan2_kernel<<<1, 1024, 0, stream>>>(dag_cnt, nd, obs_cnt, no, dag_starts, obs_starts);

    // K1: expand segment ids to nodes
    expand_ids_kernel<<<nd + no, 128, 0, stream>>>(dag_starts, nd, obs_starts, no, dag_ids, obs_ids);

    // K2: per-segment layer-1 partials
    {
        int total = (nd + no) * 32;
        seg_h1_kernel<<<(total + 255) / 256, 256, 0, stream>>>(
            dag_sum, nd, glob_sum, no, W1, b1, dag_h1, glob_h1);
    }

    // K3: main MLP + scores + per-block online softmax
    mlp_score_kernel<<<main_blocks, BLK, 0, stream>>>(
        x, emb, dag_h1, glob_h1, dag_ids, obs_ids, mask,
        W1, W2, b2, W3, b3, W4, b4, scores, blk_m, blk_s, N);

    // K4: merge -> gmax, Z
    merge_kernel<<<1, 1024, 0, stream>>>(blk_m, blk_s, main_blocks, gmax, Z);

    // K5: finalize
    finalize_kernel<<<(N + BLK - 1) / BLK, BLK, 0, stream>>>(scores, N, gmax, Z, outp);
}

// Round 5
// 4681.424 us; speedup vs baseline: 1.2427x; 1.2427x over previous
//
#include <hip/hip_runtime.h>
#include <math.h>
#include <float.h>

#define BLK 256
#define NPT 2                      // nodes per thread (spill-safe register blocking)
#define TILE (BLK * NPT)           // 512 nodes per block

// ---------------------------------------------------------------------------
// K0: fast exclusive scan of both count arrays. One block, 1024 threads.
// ---------------------------------------------------------------------------
__device__ __forceinline__ void scan_one(const int* __restrict__ cnt, int n,
                                         int* __restrict__ starts, int* wsum)
{
    const int t = threadIdx.x;
    const int chunk = (n + 1023) / 1024;
    const int base = t * chunk;

    int sum = 0;
    for (int k = 0; k < chunk; k++) {
        int idx = base + k;
        if (idx < n) sum += cnt[idx];
    }

    const int lane = t & 63, wid = t >> 6;
    int v = sum;
#pragma unroll
    for (int off = 1; off < 64; off <<= 1) {
        int y = __shfl_up(v, off);
        if (lane >= off) v += y;
    }
    if (lane == 63) wsum[wid] = v;
    __syncthreads();
    if (wid == 0) {
        int w = (lane < 16) ? wsum[lane] : 0;
#pragma unroll
        for (int off = 1; off < 16; off <<= 1) {
            int y = __shfl_up(w, off);
            if (lane >= off) w += y;
        }
        if (lane < 16) wsum[lane] = w;
    }
    __syncthreads();

    int thr_excl = ((wid > 0) ? wsum[wid - 1] : 0) + v - sum;
    int run = thr_excl;
    for (int k = 0; k < chunk; k++) {
        int idx = base + k;
        if (idx < n) { starts[idx] = run; run += cnt[idx]; }
    }
    if (t == 0) starts[n] = wsum[15];
    __syncthreads();
}

__global__ __launch_bounds__(1024) void scan2_kernel(
    const int* __restrict__ dag_cnt, int nd,
    const int* __restrict__ obs_cnt, int no,
    int* __restrict__ dag_starts, int* __restrict__ obs_starts)
{
    __shared__ int wsum[16];
    scan_one(dag_cnt, nd, dag_starts, wsum);
    scan_one(obs_cnt, no, obs_starts, wsum);
}

// ---------------------------------------------------------------------------
// K1: expand segment ids to per-node arrays (one block per segment).
// ---------------------------------------------------------------------------
__global__ __launch_bounds__(128) void expand_ids_kernel(
    const int* __restrict__ dag_starts, int nd,
    const int* __restrict__ obs_starts, int no,
    int* __restrict__ dag_ids, int* __restrict__ obs_ids)
{
    int seg = blockIdx.x;
    if (seg < nd) {
        int s = dag_starts[seg], e = dag_starts[seg + 1];
        for (int i = s + threadIdx.x; i < e; i += 128) dag_ids[i] = seg;
    } else {
        int g = seg - nd;
        int s = obs_starts[g], e = obs_starts[g + 1];
        for (int i = s + threadIdx.x; i < e; i += 128) obs_ids[i] = g;
    }
}

// ---------------------------------------------------------------------------
// K2: per-segment layer-1 partials (dag rows 37..68 no bias; glob rows 69..100 +b1).
// ---------------------------------------------------------------------------
__global__ __launch_bounds__(256) void seg_h1_kernel(
    const float* __restrict__ dag_sum, int nd,
    const float* __restrict__ glob_sum, int no,
    const float* __restrict__ W1, const float* __restrict__ b1,
    float* __restrict__ dag_h1, float* __restrict__ glob_h1)
{
    __shared__ float Wd[32 * 32];
    __shared__ float Wg[32 * 32];
    for (int t = threadIdx.x; t < 32 * 32; t += 256) {
        int k = t / 32, j = t % 32;
        Wd[t] = W1[(size_t)(37 + k) * 32 + j];
        Wg[t] = W1[(size_t)(69 + k) * 32 + j];
    }
    __syncthreads();

    int gid = blockIdx.x * 256 + threadIdx.x;
    int seg = gid / 32;
    int j   = gid % 32;
    if (seg >= nd + no) return;

    const float* srow;
    const float* Wl;
    float acc;
    float* outp;
    if (seg < nd) {
        srow = dag_sum + (size_t)seg * 32;
        Wl = Wd; acc = 0.f;
        outp = dag_h1 + (size_t)seg * 32 + j;
    } else {
        srow = glob_sum + (size_t)(seg - nd) * 32;
        Wl = Wg; acc = b1[j];
        outp = glob_h1 + (size_t)(seg - nd) * 32 + j;
    }
#pragma unroll
    for (int k = 0; k < 32; k++)
        acc = fmaf(srow[k], Wl[k * 32 + j], acc);
    *outp = acc;
}

// ---------------------------------------------------------------------------
// K3: main MLP, NPT=2 register-blocked. 512 nodes per block.
// Live set ~140 VGPRs (h1[2][32]+h2[2][16]+h3[2][8]) -- fits, no spill.
// ---------------------------------------------------------------------------
__global__ __launch_bounds__(BLK) void mlp_score_kernel(
    const float* __restrict__ x, const float* __restrict__ emb,
    const float* __restrict__ dag_h1, const float* __restrict__ glob_h1,
    const int* __restrict__ dag_ids, const int* __restrict__ obs_ids,
    const int* __restrict__ mask,
    const float* __restrict__ W1, const float* __restrict__ W2,
    const float* __restrict__ b2, const float* __restrict__ W3,
    const float* __restrict__ b3, const float* __restrict__ W4,
    const float* __restrict__ b4,
    float* __restrict__ scores, float* __restrict__ blk_m,
    double* __restrict__ blk_s, int N)
{
    __shared__ float W1l[37 * 32];
    __shared__ float W2l[32 * 16];
    __shared__ float W3l[16 * 8];
    __shared__ float W4l[8];
    __shared__ float b2l[16];
    __shared__ float b3l[8];
    __shared__ float b4s;

    for (int t = threadIdx.x; t < 37 * 32; t += BLK) W1l[t] = W1[t];
    for (int t = threadIdx.x; t < 32 * 16; t += BLK) W2l[t] = W2[t];
    for (int t = threadIdx.x; t < 16 * 8;  t += BLK) W3l[t] = W3[t];
    if (threadIdx.x < 8)  W4l[threadIdx.x] = W4[threadIdx.x];
    if (threadIdx.x < 16) b2l[threadIdx.x] = b2[threadIdx.x];
    if (threadIdx.x < 8)  b3l[threadIdx.x] = b3[threadIdx.x];
    if (threadIdx.x == 0) b4s = b4[0];
    __syncthreads();

    const int base = blockIdx.x * TILE + threadIdx.x;

    int  idx[NPT];
    bool val[NPT];
    int  mk[NPT];
#pragma unroll
    for (int r = 0; r < NPT; r++) {
        int i = base + r * BLK;
        val[r] = (i < N);
        idx[r] = val[r] ? i : (N - 1);   // clamped: loads safe, results discarded
        mk[r]  = mask[idx[r]];
    }

    float h1[NPT][32];
#pragma unroll
    for (int r = 0; r < NPT; r++) {
        const int d = dag_ids[idx[r]];
        const int o = obs_ids[idx[r]];
        const float4* dh = (const float4*)(dag_h1 + (size_t)d * 32);
        const float4* gh = (const float4*)(glob_h1 + (size_t)o * 32);
#pragma unroll
        for (int q = 0; q < 8; q++) {
            float4 a = dh[q], b = gh[q];
            h1[r][4 * q + 0] = a.x + b.x;
            h1[r][4 * q + 1] = a.y + b.y;
            h1[r][4 * q + 2] = a.z + b.z;
            h1[r][4 * q + 3] = a.w + b.w;
        }
    }

    // --- x phase: 5 input dims ---
    {
        float xv[NPT][5];
#pragma unroll
        for (int r = 0; r < NPT; r++) {
            const float* xr = x + (size_t)idx[r] * 5;
#pragma unroll
            for (int k = 0; k < 5; k++) xv[r][k] = xr[k];
        }
#pragma unroll
        for (int k = 0; k < 5; k++) {
#pragma unroll
            for (int jb = 0; jb < 8; jb++) {
                float4 w = *(const float4*)&W1l[k * 32 + jb * 4];
#pragma unroll
                for (int r = 0; r < NPT; r++) {
                    float v = xv[r][k];
                    h1[r][jb * 4 + 0] = fmaf(v, w.x, h1[r][jb * 4 + 0]);
                    h1[r][jb * 4 + 1] = fmaf(v, w.y, h1[r][jb * 4 + 1]);
                    h1[r][jb * 4 + 2] = fmaf(v, w.z, h1[r][jb * 4 + 2]);
                    h1[r][jb * 4 + 3] = fmaf(v, w.w, h1[r][jb * 4 + 3]);
                }
            }
        }
    }

    // --- emb phase: 32 input dims; weight row read once, used NPT times ---
#pragma unroll
    for (int q = 0; q < 8; q++) {
        float4 e[NPT];
#pragma unroll
        for (int r = 0; r < NPT; r++)
            e[r] = *(const float4*)(emb + (size_t)idx[r] * 32 + q * 4);
#pragma unroll
        for (int kk = 0; kk < 4; kk++) {
            const int k = 5 + q * 4 + kk;
#pragma unroll
            for (int jb = 0; jb < 8; jb++) {
                float4 w = *(const float4*)&W1l[k * 32 + jb * 4];
#pragma unroll
                for (int r = 0; r < NPT; r++) {
                    float v = (kk == 0) ? e[r].x : (kk == 1) ? e[r].y
                            : (kk == 2) ? e[r].z : e[r].w;
                    h1[r][jb * 4 + 0] = fmaf(v, w.x, h1[r][jb * 4 + 0]);
                    h1[r][jb * 4 + 1] = fmaf(v, w.y, h1[r][jb * 4 + 1]);
                    h1[r][jb * 4 + 2] = fmaf(v, w.z, h1[r][jb * 4 + 2]);
                    h1[r][jb * 4 + 3] = fmaf(v, w.w, h1[r][jb * 4 + 3]);
                }
            }
        }
    }
#pragma unroll
    for (int r = 0; r < NPT; r++)
#pragma unroll
        for (int j = 0; j < 32; j++) h1[r][j] = fmaxf(h1[r][j], 0.f);

    // --- layer 2: 32 -> 16 ---
    float h2[NPT][16];
#pragma unroll
    for (int r = 0; r < NPT; r++)
#pragma unroll
        for (int j = 0; j < 16; j++) h2[r][j] = b2l[j];
#pragma unroll
    for (int k = 0; k < 32; k++) {
#pragma unroll
        for (int jb = 0; jb < 4; jb++) {
            float4 w = *(const float4*)&W2l[k * 16 + jb * 4];
#pragma unroll
            for (int r = 0; r < NPT; r++) {
                float v = h1[r][k];
                h2[r][jb * 4 + 0] = fmaf(v, w.x, h2[r][jb * 4 + 0]);
                h2[r][jb * 4 + 1] = fmaf(v, w.y, h2[r][jb * 4 + 1]);
                h2[r][jb * 4 + 2] = fmaf(v, w.z, h2[r][jb * 4 + 2]);
                h2[r][jb * 4 + 3] = fmaf(v, w.w, h2[r][jb * 4 + 3]);
            }
        }
    }
#pragma unroll
    for (int r = 0; r < NPT; r++)
#pragma unroll
        for (int j = 0; j < 16; j++) h2[r][j] = fmaxf(h2[r][j], 0.f);

    // --- layer 3: 16 -> 8 ---
    float h3[NPT][8];
#pragma unroll
    for (int r = 0; r < NPT; r++)
#pragma unroll
        for (int j = 0; j < 8; j++) h3[r][j] = b3l[j];
#pragma unroll
    for (int k = 0; k < 16; k++) {
#pragma unroll
        for (int jb = 0; jb < 2; jb++) {
            float4 w = *(const float4*)&W3l[k * 8 + jb * 4];
#pragma unroll
            for (int r = 0; r < NPT; r++) {
                float v = h2[r][k];
                h3[r][jb * 4 + 0] = fmaf(v, w.x, h3[r][jb * 4 + 0]);
                h3[r][jb * 4 + 1] = fmaf(v, w.y, h3[r][jb * 4 + 1]);
                h3[r][jb * 4 + 2] = fmaf(v, w.z, h3[r][jb * 4 + 2]);
                h3[r][jb * 4 + 3] = fmaf(v, w.w, h3[r][jb * 4 + 3]);
            }
        }
    }
#pragma unroll
    for (int r = 0; r < NPT; r++)
#pragma unroll
        for (int j = 0; j < 8; j++) h3[r][j] = fmaxf(h3[r][j], 0.f);

    // --- layer 4 + masked score + per-thread online softmax ---
    float4 w40 = *(const float4*)&W4l[0];
    float4 w41 = *(const float4*)&W4l[4];
    float m = -INFINITY;
    double ssum = 0.0;
#pragma unroll
    for (int r = 0; r < NPT; r++) {
        float s = b4s;
        s = fmaf(h3[r][0], w40.x, s); s = fmaf(h3[r][1], w40.y, s);
        s = fmaf(h3[r][2], w40.z, s); s = fmaf(h3[r][3], w40.w, s);
        s = fmaf(h3[r][4], w41.x, s); s = fmaf(h3[r][5], w41.y, s);
        s = fmaf(h3[r][6], w41.z, s); s = fmaf(h3[r][7], w41.w, s);

        const bool live = val[r] && (mk[r] != 0);
        if (val[r]) scores[idx[r]] = (mk[r] != 0) ? s : -FLT_MAX;
        if (live) {
            if (s > m) { ssum *= (double)expf(m - s); m = s; }
            ssum += (double)expf(s - m);
        }
    }

    // --- block (m, sum) merge ---
    __shared__ float  mred[BLK];
    __shared__ double sred[BLK];
    mred[threadIdx.x] = m;
    sred[threadIdx.x] = ssum;
    __syncthreads();
    for (int off = BLK / 2; off > 0; off >>= 1) {
        if (threadIdx.x < off) {
            float ma = mred[threadIdx.x], mb = mred[threadIdx.x + off];
            double sa = sred[threadIdx.x], sb = sred[threadIdx.x + off];
            float M = fmaxf(ma, mb);
            double out = 0.0;
            if (ma > -INFINITY) out += sa * (double)expf(ma - M);
            if (mb > -INFINITY) out += sb * (double)expf(mb - M);
            mred[threadIdx.x] = M;
            sred[threadIdx.x] = out;
        }
        __syncthreads();
    }
    if (threadIdx.x == 0) {
        blk_m[blockIdx.x] = mred[0];
        blk_s[blockIdx.x] = sred[0];
    }
}

// ---------------------------------------------------------------------------
// K4: merge per-block (m, s) pairs -> gmax, Z. One block.
// ---------------------------------------------------------------------------
__global__ __launch_bounds__(1024) void merge_kernel(
    const float* __restrict__ bm, const double* __restrict__ bs, int n,
    float* __restrict__ gmax, double* __restrict__ Z)
{
    float m = -INFINITY;
    double s = 0.0;
    for (int i = threadIdx.x; i < n; i += 1024) {
        float mb = bm[i]; double sb = bs[i];
        float M = fmaxf(m, mb);
        double out = 0.0;
        if (m  > -INFINITY) out += s  * (double)expf(m  - M);
        if (mb > -INFINITY) out += sb * (double)expf(mb - M);
        m = M; s = out;
    }
    __shared__ float  mred[1024];
    __shared__ double sred[1024];
    mred[threadIdx.x] = m;
    sred[threadIdx.x] = s;
    __syncthreads();
    for (int off = 512; off > 0; off >>= 1) {
        if (threadIdx.x < off) {
            float ma = mred[threadIdx.x], mb = mred[threadIdx.x + off];
            double sa = sred[threadIdx.x], sb = sred[threadIdx.x + off];
            float M = fmaxf(ma, mb);
            double out = 0.0;
            if (ma > -INFINITY) out += sa * (double)expf(ma - M);
            if (mb > -INFINITY) out += sb * (double)expf(mb - M);
            mred[threadIdx.x] = M;
            sred[threadIdx.x] = out;
        }
        __syncthreads();
    }
    if (threadIdx.x == 0) { *gmax = mred[0]; *Z = sred[0]; }
}

// ---------------------------------------------------------------------------
// K5: finalize out[i] = exp(s - gmax) / Z  (masked -FLT_MAX -> exactly 0).
// ---------------------------------------------------------------------------
__global__ __launch_bounds__(BLK) void finalize_kernel(
    const float* __restrict__ scores, int N,
    const float* __restrict__ gmaxp, const double* __restrict__ Zp,
    float* __restrict__ outp)
{
    const float gm = *gmaxp;
    const float rZ = (float)(1.0 / *Zp);
    int i = blockIdx.x * BLK + threadIdx.x;
    if (i < N) outp[i] = expf(scores[i] - gm) * rZ;
}

// ---------------------------------------------------------------------------
extern "C" void kernel_launch(void* const* d_in, const int* in_sizes, int n_in,
                              void* d_out, int out_size, void* d_ws, size_t ws_size,
                              hipStream_t stream)
{
    const float* x        = (const float*)d_in[0];
    const float* emb      = (const float*)d_in[1];
    const float* dag_sum  = (const float*)d_in[2];
    const float* glob_sum = (const float*)d_in[3];
    const int*   dag_cnt  = (const int*)d_in[4];
    const int*   obs_cnt  = (const int*)d_in[5];
    const int*   mask     = (const int*)d_in[6];   // bool staged as int32
    const float* W1 = (const float*)d_in[7];
    const float* b1 = (const float*)d_in[8];
    const float* W2 = (const float*)d_in[9];
    const float* b2 = (const float*)d_in[10];
    const float* W3 = (const float*)d_in[11];
    const float* b3 = (const float*)d_in[12];
    const float* W4 = (const float*)d_in[13];
    const float* b4 = (const float*)d_in[14];
    float* outp = (float*)d_out;

    const int N  = in_sizes[0] / 5;   // 2,000,000
    const int nd = in_sizes[4];       // 20,000
    const int no = in_sizes[5];       // 1,000

    const int main_blocks = (N + TILE - 1) / TILE;   // 3907

    // --- workspace layout (16B aligned slices) ---
    char* ws = (char*)d_ws;
    size_t off = 0;
    auto alloc = [&](size_t bytes) {
        void* p = ws + off;
        off += (bytes + 15) & ~(size_t)15;
        return p;
    };
    int*    dag_starts = (int*)   alloc((size_t)(nd + 1) * sizeof(int));
    int*    obs_starts = (int*)   alloc((size_t)(no + 1) * sizeof(int));
    int*    dag_ids    = (int*)   alloc((size_t)N * sizeof(int));
    int*    obs_ids    = (int*)   alloc((size_t)N * sizeof(int));
    float*  dag_h1     = (float*) alloc((size_t)nd * 32 * sizeof(float));
    float*  glob_h1    = (float*) alloc((size_t)no * 32 * sizeof(float));
    float*  scores     = (float*) alloc((size_t)N * sizeof(float));
    float*  blk_m      = (float*) alloc((size_t)main_blocks * sizeof(float));
    double* blk_s      = (double*)alloc((size_t)main_blocks * sizeof(double));
    float*  gmax       = (float*) alloc(sizeof(float));
    double* Z          = (double*)alloc(sizeof(double));
    (void)ws_size;

    // K0: prefix scans
    scan2_kernel<<<1, 1024, 0, stream>>>(dag_cnt, nd, obs_cnt, no, dag_starts, obs_starts);

    // K1: expand segment ids to nodes
    expand_ids_kernel<<<nd + no, 128, 0, stream>>>(dag_starts, nd, obs_starts, no, dag_ids, obs_ids);

    // K2: per-segment layer-1 partials
    {
        int total = (nd + no) * 32;
        seg_h1_kernel<<<(total + 255) / 256, 256, 0, stream>>>(
            dag_sum, nd, glob_sum, no, W1, b1, dag_h1, glob_h1);
    }

    // K3: main MLP + scores + per-block online softmax
    mlp_score_kernel<<<main_blocks, BLK, 0, stream>>>(
        x, emb, dag_h1, glob_h1, dag_ids, obs_ids, mask,
        W1, W2, b2, W3, b3, W4, b4, scores, blk_m, blk_s, N);

    // K4: merge -> gmax, Z
    merge_kernel<<<1, 1024, 0, stream>>>(blk_m, blk_s, main_blocks, gmax, Z);

    // K5: finalize
    finalize_kernel<<<(N + BLK - 1) / BLK, BLK, 0, stream>>>(scores, N, gmax, Z, outp);
}

// Round 6
// 531.852 us; speedup vs baseline: 10.9384x; 8.8021x over previous
//
#include <hip/hip_runtime.h>
#include <math.h>
#include <float.h>

#define BLK 256

// ---------------------------------------------------------------------------
// K0: fast exclusive scan of both count arrays. One block, 1024 threads.
// ---------------------------------------------------------------------------
__device__ __forceinline__ void scan_one(const int* __restrict__ cnt, int n,
                                         int* __restrict__ starts, int* wsum)
{
    const int t = threadIdx.x;
    const int chunk = (n + 1023) / 1024;
    const int base = t * chunk;

    int sum = 0;
    for (int k = 0; k < chunk; k++) {
        int idx = base + k;
        if (idx < n) sum += cnt[idx];
    }

    const int lane = t & 63, wid = t >> 6;
    int v = sum;
#pragma unroll
    for (int off = 1; off < 64; off <<= 1) {
        int y = __shfl_up(v, off);
        if (lane >= off) v += y;
    }
    if (lane == 63) wsum[wid] = v;
    __syncthreads();
    if (wid == 0) {
        int w = (lane < 16) ? wsum[lane] : 0;
#pragma unroll
        for (int off = 1; off < 16; off <<= 1) {
            int y = __shfl_up(w, off);
            if (lane >= off) w += y;
        }
        if (lane < 16) wsum[lane] = w;
    }
    __syncthreads();

    int thr_excl = ((wid > 0) ? wsum[wid - 1] : 0) + v - sum;
    int run = thr_excl;
    for (int k = 0; k < chunk; k++) {
        int idx = base + k;
        if (idx < n) { starts[idx] = run; run += cnt[idx]; }
    }
    if (t == 0) starts[n] = wsum[15];
    __syncthreads();
}

__global__ __launch_bounds__(1024) void scan2_kernel(
    const int* __restrict__ dag_cnt, int nd,
    const int* __restrict__ obs_cnt, int no,
    int* __restrict__ dag_starts, int* __restrict__ obs_starts)
{
    __shared__ int wsum[16];
    scan_one(dag_cnt, nd, dag_starts, wsum);
    scan_one(obs_cnt, no, obs_starts, wsum);
}

// ---------------------------------------------------------------------------
// K1: expand segment ids to per-node arrays (one block per segment).
// ---------------------------------------------------------------------------
__global__ __launch_bounds__(128) void expand_ids_kernel(
    const int* __restrict__ dag_starts, int nd,
    const int* __restrict__ obs_starts, int no,
    int* __restrict__ dag_ids, int* __restrict__ obs_ids)
{
    int seg = blockIdx.x;
    if (seg < nd) {
        int s = dag_starts[seg], e = dag_starts[seg + 1];
        for (int i = s + threadIdx.x; i < e; i += 128) dag_ids[i] = seg;
    } else {
        int g = seg - nd;
        int s = obs_starts[g], e = obs_starts[g + 1];
        for (int i = s + threadIdx.x; i < e; i += 128) obs_ids[i] = g;
    }
}

// ---------------------------------------------------------------------------
// K2: per-segment layer-1 partials (dag rows 37..68 no bias; glob rows 69..100 +b1).
// ---------------------------------------------------------------------------
__global__ __launch_bounds__(256) void seg_h1_kernel(
    const float* __restrict__ dag_sum, int nd,
    const float* __restrict__ glob_sum, int no,
    const float* __restrict__ W1, const float* __restrict__ b1,
    float* __restrict__ dag_h1, float* __restrict__ glob_h1)
{
    __shared__ float Wd[32 * 32];
    __shared__ float Wg[32 * 32];
    for (int t = threadIdx.x; t < 32 * 32; t += 256) {
        int k = t / 32, j = t % 32;
        Wd[t] = W1[(size_t)(37 + k) * 32 + j];
        Wg[t] = W1[(size_t)(69 + k) * 32 + j];
    }
    __syncthreads();

    int gid = blockIdx.x * 256 + threadIdx.x;
    int seg = gid / 32;
    int j   = gid % 32;
    if (seg >= nd + no) return;

    const float* srow;
    const float* Wl;
    float acc;
    float* outp;
    if (seg < nd) {
        srow = dag_sum + (size_t)seg * 32;
        Wl = Wd; acc = 0.f;
        outp = dag_h1 + (size_t)seg * 32 + j;
    } else {
        srow = glob_sum + (size_t)(seg - nd) * 32;
        Wl = Wg; acc = b1[j];
        outp = glob_h1 + (size_t)(seg - nd) * 32 + j;
    }
#pragma unroll
    for (int k = 0; k < 32; k++)
        acc = fmaf(srow[k], Wl[k * 32 + j], acc);
    *outp = acc;
}

// ---------------------------------------------------------------------------
// K3: main MLP. ONE node per thread, NO grid-stride loop (minimizes live
// ranges / VGPR; proven: any accumulator-array blocking spills).
// Ordering for latency: independent global loads first, weight staging covers
// them; gathers issued right after sync; x/emb FMA block hides gather latency;
// gather results folded in at the end.
// ---------------------------------------------------------------------------
__global__ __launch_bounds__(BLK) void mlp_score_kernel(
    const float* __restrict__ x, const float* __restrict__ emb,
    const float* __restrict__ dag_h1, const float* __restrict__ glob_h1,
    const int* __restrict__ dag_ids, const int* __restrict__ obs_ids,
    const int* __restrict__ mask,
    const float* __restrict__ W1, const float* __restrict__ W2,
    const float* __restrict__ b2, const float* __restrict__ W3,
    const float* __restrict__ b3, const float* __restrict__ W4,
    const float* __restrict__ b4,
    float* __restrict__ scores, float* __restrict__ blk_m,
    double* __restrict__ blk_s, int N)
{
    __shared__ float W1l[37 * 32];
    __shared__ float W2l[32 * 16];
    __shared__ float W3l[16 * 8];
    __shared__ float Cst[33];        // [0:8)=W4, [8:24)=b2, [24:32)=b3, [32]=b4

    const int i0 = blockIdx.x * BLK + threadIdx.x;
    const bool valid = (i0 < N);
    const int i = valid ? i0 : (N - 1);   // clamp: loads safe, result discarded

    // --- early independent global loads (latency covered by weight staging) ---
    const int d  = dag_ids[i];
    const int o  = obs_ids[i];
    const int mk = mask[i];
    const float* xr = x + (size_t)i * 5;
    float xv0 = xr[0], xv1 = xr[1], xv2 = xr[2], xv3 = xr[3], xv4 = xr[4];

    // --- weight staging ---
    for (int t = threadIdx.x; t < 37 * 32; t += BLK) W1l[t] = W1[t];
    for (int t = threadIdx.x; t < 32 * 16; t += BLK) W2l[t] = W2[t];
    for (int t = threadIdx.x; t < 16 * 8;  t += BLK) W3l[t] = W3[t];
    if (threadIdx.x < 8)       Cst[threadIdx.x]      = W4[threadIdx.x];
    else if (threadIdx.x < 24) Cst[threadIdx.x]      = b2[threadIdx.x - 8];
    else if (threadIdx.x < 32) Cst[threadIdx.x]      = b3[threadIdx.x - 24];
    else if (threadIdx.x == 32) Cst[32]              = b4[0];
    __syncthreads();

    // --- issue dependent gathers now; consume AFTER the big FMA block ---
    const float4* dh = (const float4*)(dag_h1 + (size_t)d * 32);
    const float4* gh = (const float4*)(glob_h1 + (size_t)o * 32);
    float4 dq0 = dh[0], dq1 = dh[1], dq2 = dh[2], dq3 = dh[3],
           dq4 = dh[4], dq5 = dh[5], dq6 = dh[6], dq7 = dh[7];
    float4 gq0 = gh[0], gq1 = gh[1], gq2 = gh[2], gq3 = gh[3],
           gq4 = gh[4], gq5 = gh[5], gq6 = gh[6], gq7 = gh[7];

    // --- layer 1: x phase (k=0 init, k=1..4 accumulate) ---
    float h1[32];
#pragma unroll
    for (int j = 0; j < 32; j++) h1[j] = xv0 * W1l[j];
#pragma unroll
    for (int j = 0; j < 32; j++) h1[j] = fmaf(xv1, W1l[32 + j], h1[j]);
#pragma unroll
    for (int j = 0; j < 32; j++) h1[j] = fmaf(xv2, W1l[64 + j], h1[j]);
#pragma unroll
    for (int j = 0; j < 32; j++) h1[j] = fmaf(xv3, W1l[96 + j], h1[j]);
#pragma unroll
    for (int j = 0; j < 32; j++) h1[j] = fmaf(xv4, W1l[128 + j], h1[j]);

    // --- layer 1: emb phase ---
    const float4* er = (const float4*)(emb + (size_t)i * 32);
#pragma unroll
    for (int q = 0; q < 8; q++) {
        float4 e = er[q];
#pragma unroll
        for (int kk = 0; kk < 4; kk++) {
            const int k = 5 + q * 4 + kk;
            const float v = (kk == 0) ? e.x : (kk == 1) ? e.y : (kk == 2) ? e.z : e.w;
#pragma unroll
            for (int j = 0; j < 32; j++)
                h1[j] = fmaf(v, W1l[k * 32 + j], h1[j]);
        }
    }

    // --- fold in gathered per-segment partials (b1 already inside glob_h1) ---
#pragma unroll
    for (int c = 0; c < 4; c++) {
        h1[0  + c] += ((const float*)&dq0)[c] + ((const float*)&gq0)[c];
        h1[4  + c] += ((const float*)&dq1)[c] + ((const float*)&gq1)[c];
        h1[8  + c] += ((const float*)&dq2)[c] + ((const float*)&gq2)[c];
        h1[12 + c] += ((const float*)&dq3)[c] + ((const float*)&gq3)[c];
        h1[16 + c] += ((const float*)&dq4)[c] + ((const float*)&gq4)[c];
        h1[20 + c] += ((const float*)&dq5)[c] + ((const float*)&gq5)[c];
        h1[24 + c] += ((const float*)&dq6)[c] + ((const float*)&gq6)[c];
        h1[28 + c] += ((const float*)&dq7)[c] + ((const float*)&gq7)[c];
    }
#pragma unroll
    for (int j = 0; j < 32; j++) h1[j] = fmaxf(h1[j], 0.f);

    // --- layer 2: 32 -> 16 ---
    float h2[16];
#pragma unroll
    for (int j = 0; j < 16; j++) h2[j] = Cst[8 + j];
#pragma unroll
    for (int k = 0; k < 32; k++) {
        const float v = h1[k];
#pragma unroll
        for (int j = 0; j < 16; j++)
            h2[j] = fmaf(v, W2l[k * 16 + j], h2[j]);
    }
#pragma unroll
    for (int j = 0; j < 16; j++) h2[j] = fmaxf(h2[j], 0.f);

    // --- layer 3: 16 -> 8 ---
    float h3[8];
#pragma unroll
    for (int j = 0; j < 8; j++) h3[j] = Cst[24 + j];
#pragma unroll
    for (int k = 0; k < 16; k++) {
        const float v = h2[k];
#pragma unroll
        for (int j = 0; j < 8; j++)
            h3[j] = fmaf(v, W3l[k * 8 + j], h3[j]);
    }
#pragma unroll
    for (int j = 0; j < 8; j++) h3[j] = fmaxf(h3[j], 0.f);

    // --- layer 4 ---
    float s = Cst[32];
#pragma unroll
    for (int k = 0; k < 8; k++) s = fmaf(h3[k], Cst[k], s);

    const bool live = valid && (mk != 0);
    if (valid) scores[i0] = (mk != 0) ? s : -FLT_MAX;

    // --- block (m, sum) merge: thread contributes (s, 1) if live ---
    __shared__ float  mred[BLK];
    __shared__ double sred[BLK];
    mred[threadIdx.x] = live ? s : -INFINITY;
    sred[threadIdx.x] = live ? 1.0 : 0.0;
    __syncthreads();
    for (int off = BLK / 2; off > 0; off >>= 1) {
        if (threadIdx.x < off) {
            float ma = mred[threadIdx.x], mb = mred[threadIdx.x + off];
            double sa = sred[threadIdx.x], sb = sred[threadIdx.x + off];
            float M = fmaxf(ma, mb);
            double out = 0.0;
            if (ma > -INFINITY) out += sa * (double)expf(ma - M);
            if (mb > -INFINITY) out += sb * (double)expf(mb - M);
            mred[threadIdx.x] = M;
            sred[threadIdx.x] = out;
        }
        __syncthreads();
    }
    if (threadIdx.x == 0) {
        blk_m[blockIdx.x] = mred[0];
        blk_s[blockIdx.x] = sred[0];
    }
}

// ---------------------------------------------------------------------------
// K4: merge per-block (m, s) pairs -> gmax, Z. One block.
// ---------------------------------------------------------------------------
__global__ __launch_bounds__(1024) void merge_kernel(
    const float* __restrict__ bm, const double* __restrict__ bs, int n,
    float* __restrict__ gmax, double* __restrict__ Z)
{
    float m = -INFINITY;
    double s = 0.0;
    for (int i = threadIdx.x; i < n; i += 1024) {
        float mb = bm[i]; double sb = bs[i];
        float M = fmaxf(m, mb);
        double out = 0.0;
        if (m  > -INFINITY) out += s  * (double)expf(m  - M);
        if (mb > -INFINITY) out += sb * (double)expf(mb - M);
        m = M; s = out;
    }
    __shared__ float  mred[1024];
    __shared__ double sred[1024];
    mred[threadIdx.x] = m;
    sred[threadIdx.x] = s;
    __syncthreads();
    for (int off = 512; off > 0; off >>= 1) {
        if (threadIdx.x < off) {
            float ma = mred[threadIdx.x], mb = mred[threadIdx.x + off];
            double sa = sred[threadIdx.x], sb = sred[threadIdx.x + off];
            float M = fmaxf(ma, mb);
            double out = 0.0;
            if (ma > -INFINITY) out += sa * (double)expf(ma - M);
            if (mb > -INFINITY) out += sb * (double)expf(mb - M);
            mred[threadIdx.x] = M;
            sred[threadIdx.x] = out;
        }
        __syncthreads();
    }
    if (threadIdx.x == 0) { *gmax = mred[0]; *Z = sred[0]; }
}

// ---------------------------------------------------------------------------
// K5: finalize out[i] = exp(s - gmax) / Z  (masked -FLT_MAX -> exactly 0).
// ---------------------------------------------------------------------------
__global__ __launch_bounds__(BLK) void finalize_kernel(
    const float* __restrict__ scores, int N,
    const float* __restrict__ gmaxp, const double* __restrict__ Zp,
    float* __restrict__ outp)
{
    const float gm = *gmaxp;
    const float rZ = (float)(1.0 / *Zp);
    int i = blockIdx.x * BLK + threadIdx.x;
    if (i < N) outp[i] = expf(scores[i] - gm) * rZ;
}

// ---------------------------------------------------------------------------
extern "C" void kernel_launch(void* const* d_in, const int* in_sizes, int n_in,
                              void* d_out, int out_size, void* d_ws, size_t ws_size,
                              hipStream_t stream)
{
    const float* x        = (const float*)d_in[0];
    const float* emb      = (const float*)d_in[1];
    const float* dag_sum  = (const float*)d_in[2];
    const float* glob_sum = (const float*)d_in[3];
    const int*   dag_cnt  = (const int*)d_in[4];
    const int*   obs_cnt  = (const int*)d_in[5];
    const int*   mask     = (const int*)d_in[6];   // bool staged as int32
    const float* W1 = (const float*)d_in[7];
    const float* b1 = (const float*)d_in[8];
    const float* W2 = (const float*)d_in[9];
    const float* b2 = (const float*)d_in[10];
    const float* W3 = (const float*)d_in[11];
    const float* b3 = (const float*)d_in[12];
    const float* W4 = (const float*)d_in[13];
    const float* b4 = (const float*)d_in[14];
    float* outp = (float*)d_out;

    const int N  = in_sizes[0] / 5;   // 2,000,000
    const int nd = in_sizes[4];       // 20,000
    const int no = in_sizes[5];       // 1,000

    const int main_blocks = (N + BLK - 1) / BLK;   // 7813

    // --- workspace layout (16B aligned slices) ---
    char* ws = (char*)d_ws;
    size_t off = 0;
    auto alloc = [&](size_t bytes) {
        void* p = ws + off;
        off += (bytes + 15) & ~(size_t)15;
        return p;
    };
    int*    dag_starts = (int*)   alloc((size_t)(nd + 1) * sizeof(int));
    int*    obs_starts = (int*)   alloc((size_t)(no + 1) * sizeof(int));
    int*    dag_ids    = (int*)   alloc((size_t)N * sizeof(int));
    int*    obs_ids    = (int*)   alloc((size_t)N * sizeof(int));
    float*  dag_h1     = (float*) alloc((size_t)nd * 32 * sizeof(float));
    float*  glob_h1    = (float*) alloc((size_t)no * 32 * sizeof(float));
    float*  scores     = (float*) alloc((size_t)N * sizeof(float));
    float*  blk_m      = (float*) alloc((size_t)main_blocks * sizeof(float));
    double* blk_s      = (double*)alloc((size_t)main_blocks * sizeof(double));
    float*  gmax       = (float*) alloc(sizeof(float));
    double* Z          = (double*)alloc(sizeof(double));
    (void)ws_size;

    // K0: prefix scans
    scan2_kernel<<<1, 1024, 0, stream>>>(dag_cnt, nd, obs_cnt, no, dag_starts, obs_starts);

    // K1: expand segment ids to nodes
    expand_ids_kernel<<<nd + no, 128, 0, stream>>>(dag_starts, nd, obs_starts, no, dag_ids, obs_ids);

    // K2: per-segment layer-1 partials
    {
        int total = (nd + no) * 32;
        seg_h1_kernel<<<(total + 255) / 256, 256, 0, stream>>>(
            dag_sum, nd, glob_sum, no, W1, b1, dag_h1, glob_h1);
    }

    // K3: main MLP + scores + per-block softmax partials
    mlp_score_kernel<<<main_blocks, BLK, 0, stream>>>(
        x, emb, dag_h1, glob_h1, dag_ids, obs_ids, mask,
        W1, W2, b2, W3, b3, W4, b4, scores, blk_m, blk_s, N);

    // K4: merge -> gmax, Z
    merge_kernel<<<1, 1024, 0, stream>>>(blk_m, blk_s, main_blocks, gmax, Z);

    // K5: finalize
    finalize_kernel<<<(N + BLK - 1) / BLK, BLK, 0, stream>>>(scores, N, gmax, Z, outp);
}